// Round 2
// baseline (86.978 us; speedup 1.0000x reference)
//
#include <hip/hip_runtime.h>

// DNCM: collapse (x@P@Tm@Q).mean() algebraically.
// result[b] = (1/(HW*3)) * sum_c S[b,c] * rowsum[b,c]
//   S[b,c]       = spatial sum of I[b,c,:,:]
//   rowsum[b,c]  = sum_k P[c,k] * (Tm[b] @ qsum)[k],  qsum[k'] = sum_j Q[k',j]

#define HWSZ 262144   // 512*512
#define NPLANES 48    // 16*3
#define NB 32         // blocks per plane
#define BLOCK 256

__global__ __launch_bounds__(BLOCK) void plane_partial_sums(
    const float* __restrict__ I, float* __restrict__ partial) {
    const int plane = blockIdx.x / NB;
    const int chunk = blockIdx.x % NB;
    const int t = threadIdx.x;
    // each block reduces HWSZ/NB = 8192 floats = 2048 float4
    const float4* base = (const float4*)I
        + (size_t)plane * (HWSZ / 4)
        + (size_t)chunk * (HWSZ / 4 / NB);
    float acc = 0.f;
    #pragma unroll
    for (int i = 0; i < (HWSZ / 4 / NB) / BLOCK; ++i) {  // 8 iters
        float4 v = base[i * BLOCK + t];
        acc += (v.x + v.y) + (v.z + v.w);
    }
    // wave64 shuffle reduce
    #pragma unroll
    for (int o = 32; o > 0; o >>= 1) acc += __shfl_down(acc, o, 64);
    __shared__ float wsum[BLOCK / 64];
    const int wave = t >> 6;
    if ((t & 63) == 0) wsum[wave] = acc;
    __syncthreads();
    if (t == 0) partial[plane * NB + chunk] = (wsum[0] + wsum[1]) + (wsum[2] + wsum[3]);
}

__global__ __launch_bounds__(BLOCK) void finalize(
    const float* __restrict__ partial, const float* __restrict__ T,
    const float* __restrict__ P, const float* __restrict__ Q,
    float* __restrict__ out) {
    __shared__ float s[NPLANES];
    const int t = threadIdx.x;
    if (t < NPLANES) {
        float a = 0.f;
        #pragma unroll 8
        for (int j = 0; j < NB; ++j) a += partial[t * NB + j];
        s[t] = a;
    }
    __syncthreads();
    if (t < 16) {
        const int b = t;
        float qsum[16];
        #pragma unroll
        for (int k = 0; k < 16; ++k) qsum[k] = Q[k * 3 + 0] + Q[k * 3 + 1] + Q[k * 3 + 2];
        const float* Tm = T + b * 256;          // (16,16) row-major
        float u[16];
        #pragma unroll
        for (int k = 0; k < 16; ++k) {
            float a = 0.f;
            #pragma unroll
            for (int kk = 0; kk < 16; ++kk) a += Tm[k * 16 + kk] * qsum[kk];
            u[k] = a;
        }
        float r = 0.f;
        #pragma unroll
        for (int c = 0; c < 3; ++c) {
            float row = 0.f;
            #pragma unroll
            for (int k = 0; k < 16; ++k) row += P[c * 16 + k] * u[k];
            r += s[b * 3 + c] * row;
        }
        out[b] = r * (1.0f / (float)(HWSZ * 3));
    }
}

extern "C" void kernel_launch(void* const* d_in, const int* in_sizes, int n_in,
                              void* d_out, int out_size, void* d_ws, size_t ws_size,
                              hipStream_t stream) {
    const float* I = (const float*)d_in[0];   // (16,3,512,512)
    const float* T = (const float*)d_in[1];   // (16,256)
    const float* P = (const float*)d_in[2];   // (3,16)
    const float* Q = (const float*)d_in[3];   // (16,3)
    float* out = (float*)d_out;               // (16,1)
    float* partial = (float*)d_ws;            // 48*32 floats = 6 KB

    plane_partial_sums<<<NPLANES * NB, BLOCK, 0, stream>>>(I, partial);
    finalize<<<1, BLOCK, 0, stream>>>(partial, T, P, Q, out);
}